// Round 21
// baseline (89.970 us; speedup 1.0000x reference)
//
#include <hip/hip_runtime.h>
#include <hip/hip_bf16.h>
#include <math.h>

#define D_CH   256
#define NHEAD  4
#define DHEAD  64
#define NPTS   4096
#define KSPLIT 8
#define KCHUNK (NPTS / KSPLIT)          // 512 keys = 8 tiles of 64
#define BN_RSQ 0.99999500003749963f     // 1/sqrt(1 + 1e-5)
#define HSTRIDE 262144                  // 4096*64 ushorts per head

typedef __attribute__((ext_vector_type(4))) float f32x4;
typedef __attribute__((ext_vector_type(8))) short bf16x8;
typedef unsigned short ushort_t;

__device__ __forceinline__ ushort_t f2bf(float x) {
    unsigned int b = __float_as_uint(x);
    return (ushort_t)((b + 0x7FFF + ((b >> 16) & 1)) >> 16);  // RNE (scalar fallback)
}
__device__ __forceinline__ float bf2f(ushort_t u) {
    return __uint_as_float(((unsigned int)u) << 16);
}
// HW packed f32x2 -> bf16x2 (RNE), single VALU op (T12 primitive, m240)
__device__ __forceinline__ unsigned cvt_pk(float lo, float hi) {
    unsigned r;
    asm("v_cvt_pk_bf16_f32 %0, %1, %2" : "=v"(r) : "v"(lo), "v"(hi));
    return r;
}

// ---------------------------------------------------------------------------
// Fused QKV projection with in-kernel x transpose. r21: grid (64,2,3) with a
// 2-iteration m-loop (staging redundancy 12x -> 6x) and vectorized staging
// (f32x4 loads + cvt_pk pair conversion). 0.125 folded into Q.
// ---------------------------------------------------------------------------
__global__ __launch_bounds__(256) void gemm_qkv(
    const float* __restrict__ Wq, const float* __restrict__ bq,
    const float* __restrict__ Wk, const float* __restrict__ bk,
    const float* __restrict__ Wv, const float* __restrict__ bv,
    const float* __restrict__ x,
    ushort_t* __restrict__ Qf, ushort_t* __restrict__ Kf, ushort_t* __restrict__ Vf)
{
    __shared__ __align__(16) ushort_t Bs[64][266];   // [n][k] bf16, 34048 B

    const int tid = threadIdx.x;
    const int w = tid >> 6, lane = tid & 63, l15 = lane & 15, lhi = lane >> 4;
    const int wm = w >> 1, wn = w & 1;
    const int nb = blockIdx.x * 64;
    const int my = blockIdx.y;          // 0..1: 128-row half of the M dim
    const int z = blockIdx.z;

    // stage: f32x4 coalesced reads -> cvt_pk -> bf16 transpose-store
#pragma unroll
    for (int p = 0; p < 16; ++p) {
        int id4 = p * 256 + tid;        // 0..4095
        int kk  = id4 >> 4;             // 0..255
        int nn  = (id4 & 15) * 4;       // 0..60
        f32x4 v = *(const f32x4*)&x[(size_t)kk * NPTS + nb + nn];
        unsigned lo = cvt_pk(v[0], v[1]);
        unsigned hi = cvt_pk(v[2], v[3]);
        Bs[nn][kk]     = (ushort_t)(lo & 0xFFFF);
        Bs[nn + 1][kk] = (ushort_t)(lo >> 16);
        Bs[nn + 2][kk] = (ushort_t)(hi & 0xFFFF);
        Bs[nn + 3][kk] = (ushort_t)(hi >> 16);
    }
    __syncthreads();

    const float* A    = (z == 0) ? Wq : (z == 1) ? Wk : Wv;
    const float* bias = (z == 0) ? bq : (z == 1) ? bk : bv;
    ushort_t* dst     = (z == 0) ? Qf : (z == 1) ? Kf : Vf;
    const float scl   = (z == 0) ? 0.125f : 1.0f;

#pragma unroll
    for (int it = 0; it < 2; ++it) {
        const int m0 = my * 128 + it * 64 + wm * 32;

        f32x4 acc[2][2];
#pragma unroll
        for (int i = 0; i < 2; ++i)
#pragma unroll
            for (int j = 0; j < 2; ++j) acc[i][j] = (f32x4){0.f, 0.f, 0.f, 0.f};

        for (int k0 = 0; k0 < D_CH; k0 += 32) {
            bf16x8 af[2], bfr[2];
#pragma unroll
            for (int mf = 0; mf < 2; ++mf) {
                const float* ap = A + (size_t)(m0 + mf * 16 + l15) * D_CH + k0 + lhi * 8;
                float4 a0 = *(const float4*)ap;
                float4 a1 = *(const float4*)(ap + 4);
                unsigned* tp = (unsigned*)&af[mf];
                tp[0] = cvt_pk(a0.x, a0.y);
                tp[1] = cvt_pk(a0.z, a0.w);
                tp[2] = cvt_pk(a1.x, a1.y);
                tp[3] = cvt_pk(a1.z, a1.w);
            }
#pragma unroll
            for (int nf = 0; nf < 2; ++nf)
                bfr[nf] = *(const bf16x8*)&Bs[wn * 32 + nf * 16 + l15][k0 + lhi * 8];
#pragma unroll
            for (int mf = 0; mf < 2; ++mf)
#pragma unroll
                for (int nf = 0; nf < 2; ++nf)
                    acc[mf][nf] = __builtin_amdgcn_mfma_f32_16x16x32_bf16(af[mf], bfr[nf], acc[mf][nf], 0, 0, 0);
        }

#pragma unroll
        for (int mf = 0; mf < 2; ++mf) {
#pragma unroll
            for (int r = 0; r < 4; ++r) {
                int m = m0 + mf * 16 + lhi * 4 + r;
                int head = m >> 6, dch = m & 63;
                float bi = bias[m];
#pragma unroll
                for (int nf = 0; nf < 2; ++nf) {
                    int n = nb + wn * 32 + nf * 16 + l15;
                    float v = (acc[mf][nf][r] + bi) * scl;
                    size_t idx;
                    if (z < 2)
                        idx = (size_t)head * HSTRIDE + (size_t)(n >> 4) * 1024 + (dch >> 5) * 512
                            + (((dch >> 3) & 3) * 16 + (n & 15)) * 8 + (dch & 7);
                    else
                        idx = (size_t)head * HSTRIDE + (size_t)(n >> 6) * 4096 + (dch >> 4) * 1024
                            + ((n >> 5) & 1) * 512 + (((n >> 3) & 3) * 16 + (dch & 15)) * 8 + (n & 7);
                    dst[idx] = (ushort_t)(cvt_pk(v, v) & 0xFFFF);
                }
            }
        }
    }
}

// ---------------------------------------------------------------------------
// One 64-key attention tile (r18/r20 ordering — measured best).
// ---------------------------------------------------------------------------
__device__ __forceinline__ void attn_tile(
    int kt, int ktn, const float* __restrict__ Sg,
    const ushort_t* __restrict__ Kh, const ushort_t* __restrict__ Vh,
    const bf16x8 (&qf)[2][2],
    ushort_t (* __restrict__ Sw)[72],
    f32x4 (&macc)[2][4], float (&lrun)[2],
    ushort_t (* __restrict__ Pw)[72], int l15, int lhi, int lane)
{
    // issue next tile's mask loads (8 instr, 4x256B segments each)
    f32x4 sr[8];
#pragma unroll
    for (int p = 0; p < 8; ++p)
        sr[p] = *(const f32x4*)&Sg[(size_t)p * 4 * NPTS + (size_t)ktn * 64];

    // QK^T swapped for both q-frags: sacc[f][kb][r] = score[key][q=f*16+l15]
    f32x4 sacc0[4], sacc1[4];
    __builtin_amdgcn_s_setprio(1);
#pragma unroll
    for (int kb = 0; kb < 4; ++kb) {
        const ushort_t* kp = Kh + (size_t)(kt * 4 + kb) * 1024 + lane * 8;
        bf16x8 kf0 = *(const bf16x8*)kp;
        bf16x8 kf1 = *(const bf16x8*)(kp + 512);
        f32x4 z0 = (f32x4){0.f, 0.f, 0.f, 0.f};
        z0 = __builtin_amdgcn_mfma_f32_16x16x32_bf16(kf0, qf[0][0], z0, 0, 0, 0);
        z0 = __builtin_amdgcn_mfma_f32_16x16x32_bf16(kf1, qf[0][1], z0, 0, 0, 0);
        sacc0[kb] = z0;
        f32x4 z1 = (f32x4){0.f, 0.f, 0.f, 0.f};
        z1 = __builtin_amdgcn_mfma_f32_16x16x32_bf16(kf0, qf[1][0], z1, 0, 0, 0);
        z1 = __builtin_amdgcn_mfma_f32_16x16x32_bf16(kf1, qf[1][1], z1, 0, 0, 0);
        sacc1[kb] = z1;
    }
    __builtin_amdgcn_s_setprio(0);

    // issue V loads (shared by both fragments)
    bf16x8 vf[8];
    const ushort_t* vb = Vh + (size_t)kt * 4096 + lane * 8;
#pragma unroll
    for (int mm = 0; mm < 2; ++mm)
#pragma unroll
        for (int db = 0; db < 4; ++db)
            vf[mm * 4 + db] = *(const bf16x8*)(vb + db * 1024 + mm * 512);

    // p = exp(score * mask), both fragments; pack (HW cvt) -> P_lds
    float ts0 = 0.0f, ts1 = 0.0f;
#pragma unroll
    for (int kb = 0; kb < 4; ++kb) {
        unsigned a0 = *(const unsigned*)&Sw[l15][kb * 16 + lhi * 4];
        unsigned a1 = *(const unsigned*)&Sw[l15][kb * 16 + lhi * 4 + 2];
        unsigned b0 = *(const unsigned*)&Sw[16 + l15][kb * 16 + lhi * 4];
        unsigned b1 = *(const unsigned*)&Sw[16 + l15][kb * 16 + lhi * 4 + 2];
        float p00 = __expf(sacc0[kb][0] * bf2f((ushort_t)(a0 & 0xFFFF)));
        float p01 = __expf(sacc0[kb][1] * bf2f((ushort_t)(a0 >> 16)));
        float p02 = __expf(sacc0[kb][2] * bf2f((ushort_t)(a1 & 0xFFFF)));
        float p03 = __expf(sacc0[kb][3] * bf2f((ushort_t)(a1 >> 16)));
        float p10 = __expf(sacc1[kb][0] * bf2f((ushort_t)(b0 & 0xFFFF)));
        float p11 = __expf(sacc1[kb][1] * bf2f((ushort_t)(b0 >> 16)));
        float p12 = __expf(sacc1[kb][2] * bf2f((ushort_t)(b1 & 0xFFFF)));
        float p13 = __expf(sacc1[kb][3] * bf2f((ushort_t)(b1 >> 16)));
        ts0 += (p00 + p01) + (p02 + p03);
        ts1 += (p10 + p11) + (p12 + p13);
        *(unsigned*)&Pw[l15][kb * 16 + lhi * 4]          = cvt_pk(p00, p01);
        *(unsigned*)&Pw[l15][kb * 16 + lhi * 4 + 2]      = cvt_pk(p02, p03);
        *(unsigned*)&Pw[16 + l15][kb * 16 + lhi * 4]     = cvt_pk(p10, p11);
        *(unsigned*)&Pw[16 + l15][kb * 16 + lhi * 4 + 2] = cvt_pk(p12, p13);
    }
    lrun[0] += ts0;
    lrun[1] += ts1;

    // store next tile's mask (all Sw reads done; sr regs die here)
#pragma unroll
    for (int p = 0; p < 8; ++p) {
        *(unsigned*)&Sw[p * 4 + lhi][l15 * 4]     = cvt_pk(sr[p][0], sr[p][1]);
        *(unsigned*)&Sw[p * 4 + lhi][l15 * 4 + 2] = cvt_pk(sr[p][2], sr[p][3]);
    }

    // PV: mfma(A=V row=d, B=P col=q), both fragments share vf
    __builtin_amdgcn_s_setprio(1);
#pragma unroll
    for (int mm = 0; mm < 2; ++mm) {
        bf16x8 pf0 = *(const bf16x8*)&Pw[l15][mm * 32 + lhi * 8];
        bf16x8 pf1 = *(const bf16x8*)&Pw[16 + l15][mm * 32 + lhi * 8];
#pragma unroll
        for (int db = 0; db < 4; ++db) {
            macc[0][db] = __builtin_amdgcn_mfma_f32_16x16x32_bf16(vf[mm * 4 + db], pf0, macc[0][db], 0, 0, 0);
            macc[1][db] = __builtin_amdgcn_mfma_f32_16x16x32_bf16(vf[mm * 4 + db], pf1, macc[1][db], 0, 0, 0);
        }
    }
    __builtin_amdgcn_s_setprio(0);
}

// ---------------------------------------------------------------------------
// MFMA flash attention (r20 form, unchanged): 32 q/warp, per-head blocks,
// key-split 8. Grid (32, NHEAD, KSPLIT); block 256.
// ---------------------------------------------------------------------------
__global__ __launch_bounds__(256, 3) void attn_mfma(
    const ushort_t* __restrict__ Qf, const ushort_t* __restrict__ Kf,
    const ushort_t* __restrict__ Vf, const float* __restrict__ S,
    ushort_t* __restrict__ pacc, float* __restrict__ pl)
{
    __shared__ __align__(16) ushort_t P_lds[4][32][72];   // 18432 B
    __shared__ __align__(16) ushort_t S_lds[4][32][72];   // 18432 B

    const int tid  = threadIdx.x;
    const int w    = tid >> 6;
    const int lane = tid & 63;
    const int l15  = lane & 15;
    const int lhi  = lane >> 4;
    const int h    = blockIdx.y;
    const int ks   = blockIdx.z;
    const int q0   = blockIdx.x * 128 + w * 32;
    const int ktb  = ks * (KCHUNK / 64);

    const ushort_t* Kh = Kf + (size_t)h * HSTRIDE;
    const ushort_t* Vh = Vf + (size_t)h * HSTRIDE;
    const float* Sg = S + (size_t)(q0 + lhi) * NPTS + l15 * 4;
    ushort_t (* __restrict__ Pw)[72] = P_lds[w];
    ushort_t (* __restrict__ Sw)[72] = S_lds[w];

    bf16x8 qf[2][2];
#pragma unroll
    for (int f = 0; f < 2; ++f) {
        const ushort_t* qp = Qf + (size_t)h * HSTRIDE
                           + (size_t)((q0 + f * 16) >> 4) * 1024 + lane * 8;
        qf[f][0] = *(const bf16x8*)qp;
        qf[f][1] = *(const bf16x8*)(qp + 512);
    }

    f32x4 macc[2][4];
#pragma unroll
    for (int f = 0; f < 2; ++f)
#pragma unroll
        for (int db = 0; db < 4; ++db) macc[f][db] = (f32x4){0.f, 0.f, 0.f, 0.f};
    float lrun[2] = {0.0f, 0.0f};

    // prologue: stage mask tile ktb
    {
#pragma unroll
        for (int p = 0; p < 8; ++p) {
            f32x4 t = *(const f32x4*)&Sg[(size_t)p * 4 * NPTS + (size_t)ktb * 64];
            *(unsigned*)&Sw[p * 4 + lhi][l15 * 4]     = cvt_pk(t[0], t[1]);
            *(unsigned*)&Sw[p * 4 + lhi][l15 * 4 + 2] = cvt_pk(t[2], t[3]);
        }
    }

    // 8 tiles; prefetch distance 1 (wrap on last is harmless)
    for (int kt = ktb; kt < ktb + 8; ++kt) {
        const int ktn = (kt + 1 < ktb + 8) ? kt + 1 : ktb;
        attn_tile(kt, ktn, Sg, Kh, Vh, qf, Sw, macc, lrun, Pw, l15, lhi, lane);
    }

    // deferred cross-group l reduction (once per block)
#pragma unroll
    for (int f = 0; f < 2; ++f) {
        lrun[f] += __shfl_xor(lrun[f], 16);
        lrun[f] += __shfl_xor(lrun[f], 32);
    }

    // store unnormalized partials for both fragments
    const size_t pb = ((size_t)ks * NHEAD + h) * NPTS;
#pragma unroll
    for (int f = 0; f < 2; ++f) {
        ushort_t* prow = pacc + (pb + q0 + f * 16 + l15) * DHEAD;
#pragma unroll
        for (int db = 0; db < 4; ++db) {
            *(unsigned*)&prow[db * 16 + lhi * 4]     = cvt_pk(macc[f][db][0], macc[f][db][1]);
            *(unsigned*)&prow[db * 16 + lhi * 4 + 2] = cvt_pk(macc[f][db][2], macc[f][db][3]);
        }
    }
    if (lane < 16) {
        pl[pb + q0 + lane]      = lrun[0];
        pl[pb + q0 + 16 + lane] = lrun[1];
    }
}

// ---------------------------------------------------------------------------
// FUSED MERGE + MLP on 16-point blocks (r19/r20 form, unchanged).
// ---------------------------------------------------------------------------
__global__ __launch_bounds__(256) void mlp_fused(
    const ushort_t* __restrict__ pacc, const float* __restrict__ pl,
    ushort_t* __restrict__ msgT,
    const float* __restrict__ W1, const float* __restrict__ b1,
    const float* __restrict__ g1, const float* __restrict__ be1,
    const float* __restrict__ W2, const float* __restrict__ b2,
    const float* __restrict__ g2, const float* __restrict__ be2,
    const float* __restrict__ W3, const float* __restrict__ b3,
    const float* __restrict__ x, float* __restrict__ out,
    ushort_t* __restrict__ h1T, ushort_t* __restrict__ h2T)
{
    const int tid = threadIdx.x;
    const int w = tid >> 6, lane = tid & 63, l15 = lane & 15, lhi = lane >> 4;
    const int nblk = blockIdx.x * 16;

    // --- Phase A: merge partials -> msgT (16 rows; 2 heads per thread-half)
    {
        const int hb  = (tid >> 7) * 2;       // 0 or 2
        const int loc = tid & 127;
        const int ql  = loc >> 3;             // 0..15
        const int d0  = (loc & 7) * 8;        // 0..56
#pragma unroll
        for (int hh = 0; hh < 2; ++hh) {
            const int h = hb + hh;
            float ls = 0.0f;
#pragma unroll
            for (int ks = 0; ks < KSPLIT; ++ks)
                ls += pl[((size_t)ks * NHEAD + h) * NPTS + nblk + ql];
            float inv = 1.0f / ls;
            float o[8];
#pragma unroll
            for (int j = 0; j < 8; ++j) o[j] = 0.0f;
#pragma unroll
            for (int ks = 0; ks < KSPLIT; ++ks) {
                const ushort_t* ap = pacc
                    + (((size_t)ks * NHEAD + h) * NPTS + nblk + ql) * DHEAD + d0;
                bf16x8 v = *(const bf16x8*)ap;
#pragma unroll
                for (int j = 0; j < 8; ++j) o[j] += bf2f((ushort_t)v[j]);
            }
            unsigned* dp = (unsigned*)(msgT + (size_t)(nblk + ql) * D_CH + h * 64 + d0);
            dp[0] = cvt_pk(o[0] * inv, o[1] * inv);
            dp[1] = cvt_pk(o[2] * inv, o[3] * inv);
            dp[2] = cvt_pk(o[4] * inv, o[5] * inv);
            dp[3] = cvt_pk(o[6] * inv, o[7] * inv);
        }
    }
    __syncthreads();

    // --- Phase B: h1 = relu(bn1(W1 . msg)), M=128 K=256, n=16 --------------
    {
        f32x4 acc[2];
        acc[0] = (f32x4){0.f, 0.f, 0.f, 0.f};
        acc[1] = (f32x4){0.f, 0.f, 0.f, 0.f};
        const ushort_t* Bt = msgT + (size_t)nblk * D_CH;
        for (int k0 = 0; k0 < 256; k0 += 32) {
            bf16x8 bfr = *(const bf16x8*)&Bt[(size_t)l15 * D_CH + k0 + lhi * 8];
#pragma unroll
            for (int mf = 0; mf < 2; ++mf) {
                const float* ap = W1 + (size_t)(w * 32 + mf * 16 + l15) * 256 + k0 + lhi * 8;
                float4 a0 = *(const float4*)ap;
                float4 a1 = *(const float4*)(ap + 4);
                bf16x8 af;
                unsigned* tp = (unsigned*)&af;
                tp[0] = cvt_pk(a0.x, a0.y); tp[1] = cvt_pk(a0.z, a0.w);
                tp[2] = cvt_pk(a1.x, a1.y); tp[3] = cvt_pk(a1.z, a1.w);
                acc[mf] = __builtin_amdgcn_mfma_f32_16x16x32_bf16(af, bfr, acc[mf], 0, 0, 0);
            }
        }
#pragma unroll
        for (int mf = 0; mf < 2; ++mf)
#pragma unroll
            for (int r = 0; r < 4; ++r) {
                int m = w * 32 + mf * 16 + lhi * 4 + r;
                float bi = b1[m], sc = g1[m] * BN_RSQ, sh = be1[m];
                float v = fmaxf((acc[mf][r] + bi) * sc + sh, 0.0f);
                h1T[(size_t)(nblk + l15) * 128 + m] = (ushort_t)(cvt_pk(v, v) & 0xFFFF);
            }
    }
    __syncthreads();

    // --- Phase C: h2 = relu(bn2(W2 . h1)), M=128 K=128, n=16 ----------------
    {
        f32x4 acc[2];
        acc[0] = (f32x4){0.f, 0.f, 0.f, 0.f};
        acc[1] = (f32x4){0.f, 0.f, 0.f, 0.f};
        const ushort_t* Bt = h1T + (size_t)nblk * 128;
        for (int k0 = 0; k0 < 128; k0 += 32) {
            bf16x8 bfr = *(const bf16x8*)&Bt[(size_t)l15 * 128 + k0 + lhi * 8];
#pragma unroll
            for (int mf = 0; mf < 2; ++mf) {
                const float* ap = W2 + (size_t)(w * 32 + mf * 16 + l15) * 128 + k0 + lhi * 8;
                float4 a0 = *(const float4*)ap;
                float4 a1 = *(const float4*)(ap + 4);
                bf16x8 af;
                unsigned* tp = (unsigned*)&af;
                tp[0] = cvt_pk(a0.x, a0.y); tp[1] = cvt_pk(a0.z, a0.w);
                tp[2] = cvt_pk(a1.x, a1.y); tp[3] = cvt_pk(a1.z, a1.w);
                acc[mf] = __builtin_amdgcn_mfma_f32_16x16x32_bf16(af, bfr, acc[mf], 0, 0, 0);
            }
        }
#pragma unroll
        for (int mf = 0; mf < 2; ++mf)
#pragma unroll
            for (int r = 0; r < 4; ++r) {
                int m = w * 32 + mf * 16 + lhi * 4 + r;
                float bi = b2[m], sc = g2[m] * BN_RSQ, sh = be2[m];
                float v = fmaxf((acc[mf][r] + bi) * sc + sh, 0.0f);
                h2T[(size_t)(nblk + l15) * 128 + m] = (ushort_t)(cvt_pk(v, v) & 0xFFFF);
            }
    }
    __syncthreads();

    // --- Phase D: out = x + W3 . h2, M=256 K=128, n=16 ----------------------
    {
        f32x4 acc[4];
#pragma unroll
        for (int i = 0; i < 4; ++i) acc[i] = (f32x4){0.f, 0.f, 0.f, 0.f};
        const ushort_t* Bt = h2T + (size_t)nblk * 128;
        for (int k0 = 0; k0 < 128; k0 += 32) {
            bf16x8 bfr = *(const bf16x8*)&Bt[(size_t)l15 * 128 + k0 + lhi * 8];
#pragma unroll
            for (int mf = 0; mf < 4; ++mf) {
                const float* ap = W3 + (size_t)(w * 64 + mf * 16 + l15) * 128 + k0 + lhi * 8;
                float4 a0 = *(const float4*)ap;
                float4 a1 = *(const float4*)(ap + 4);
                bf16x8 af;
                unsigned* tp = (unsigned*)&af;
                tp[0] = cvt_pk(a0.x, a0.y); tp[1] = cvt_pk(a0.z, a0.w);
                tp[2] = cvt_pk(a1.x, a1.y); tp[3] = cvt_pk(a1.z, a1.w);
                acc[mf] = __builtin_amdgcn_mfma_f32_16x16x32_bf16(af, bfr, acc[mf], 0, 0, 0);
            }
        }
#pragma unroll
        for (int mf = 0; mf < 4; ++mf)
#pragma unroll
            for (int r = 0; r < 4; ++r) {
                int m = w * 64 + mf * 16 + lhi * 4 + r;
                float bi = b3[m];
                int n = nblk + l15;
                out[(size_t)m * NPTS + n] = acc[mf][r] + bi + x[(size_t)m * NPTS + n];
            }
    }
}

// ---------------------------------------------------------------------------
extern "C" void kernel_launch(void* const* d_in, const int* in_sizes, int n_in,
                              void* d_out, int out_size, void* d_ws, size_t ws_size,
                              hipStream_t stream) {
    const float* x  = (const float*)d_in[0];
    const float* S  = (const float*)d_in[1];
    const float* Wq = (const float*)d_in[2];
    const float* bq = (const float*)d_in[3];
    const float* Wk = (const float*)d_in[4];
    const float* bk = (const float*)d_in[5];
    const float* Wv = (const float*)d_in[6];
    const float* bv = (const float*)d_in[7];
    const float* W1 = (const float*)d_in[8];
    const float* b1 = (const float*)d_in[9];
    const float* g1 = (const float*)d_in[10];
    const float* be1= (const float*)d_in[11];
    const float* W2 = (const float*)d_in[12];
    const float* b2 = (const float*)d_in[13];
    const float* g2 = (const float*)d_in[14];
    const float* be2= (const float*)d_in[15];
    const float* W3 = (const float*)d_in[16];
    const float* b3 = (const float*)d_in[17];

    char* ws = (char*)d_ws;
    const size_t MB = 1024 * 1024;
    ushort_t* Qf   = (ushort_t*)(ws + 2 * MB);               // 2 MB
    ushort_t* Kf   = (ushort_t*)(ws + 4 * MB);               // 2 MB
    ushort_t* Vf   = (ushort_t*)(ws + 6 * MB);               // 2 MB
    ushort_t* pacc = (ushort_t*)(ws + 8 * MB);               // 16 MB
    float*    pl   = (float*)   (ws + 24 * MB);              // 512 KB
    ushort_t* msgT = (ushort_t*)(ws + 25 * MB);              // 2 MB
    ushort_t* h1T  = (ushort_t*)(ws + 27 * MB);              // 1 MB
    ushort_t* h2T  = (ushort_t*)(ws + 28 * MB);              // 1 MB

    gemm_qkv<<<dim3(64, 2, 3), 256, 0, stream>>>(Wq, bq, Wk, bk, Wv, bv, x, Qf, Kf, Vf);

    attn_mfma<<<dim3(32, NHEAD, KSPLIT), 256, 0, stream>>>(Qf, Kf, Vf, S, pacc, pl);

    mlp_fused<<<dim3(256), 256, 0, stream>>>(pacc, pl, msgT,
        W1, b1, g1, be1, W2, b2, g2, be2, W3, b3, x, (float*)d_out, h1T, h2T);
}

// Round 22
// 85.753 us; speedup vs baseline: 1.0492x; 1.0492x over previous
//
#include <hip/hip_runtime.h>
#include <hip/hip_bf16.h>
#include <math.h>

#define D_CH   256
#define NHEAD  4
#define DHEAD  64
#define NPTS   4096
#define KSPLIT 8
#define KCHUNK (NPTS / KSPLIT)          // 512 keys = 8 tiles of 64
#define BN_RSQ 0.99999500003749963f     // 1/sqrt(1 + 1e-5)
#define HSTRIDE 262144                  // 4096*64 ushorts per head

typedef __attribute__((ext_vector_type(4))) float f32x4;
typedef __attribute__((ext_vector_type(8))) short bf16x8;
typedef unsigned short ushort_t;

__device__ __forceinline__ ushort_t f2bf(float x) {
    unsigned int b = __float_as_uint(x);
    return (ushort_t)((b + 0x7FFF + ((b >> 16) & 1)) >> 16);  // RNE (scalar fallback)
}
__device__ __forceinline__ float bf2f(ushort_t u) {
    return __uint_as_float(((unsigned int)u) << 16);
}
// HW packed f32x2 -> bf16x2 (RNE), single VALU op (T12 primitive, m240)
__device__ __forceinline__ unsigned cvt_pk(float lo, float hi) {
    unsigned r;
    asm("v_cvt_pk_bf16_f32 %0, %1, %2" : "=v"(r) : "v"(lo), "v"(hi));
    return r;
}

// ---------------------------------------------------------------------------
// Fused QKV projection with IN-KERNEL x transpose (r20 form, measured best):
// stage x[0:256][nb:nb+64] -> Bs[n][k] bf16 in LDS, then the MFMA k-loop
// reads B-fragments from LDS. 0.125 folded into Q. Grid (64, 4, 3).
// ---------------------------------------------------------------------------
__global__ __launch_bounds__(256) void gemm_qkv(
    const float* __restrict__ Wq, const float* __restrict__ bq,
    const float* __restrict__ Wk, const float* __restrict__ bk,
    const float* __restrict__ Wv, const float* __restrict__ bv,
    const float* __restrict__ x,
    ushort_t* __restrict__ Qf, ushort_t* __restrict__ Kf, ushort_t* __restrict__ Vf)
{
    __shared__ __align__(16) ushort_t Bs[64][266];   // [n][k] bf16, 34048 B

    const int tid = threadIdx.x;
    const int w = tid >> 6, lane = tid & 63, l15 = lane & 15, lhi = lane >> 4;
    const int wm = w >> 1, wn = w & 1;
    const int m0 = blockIdx.y * 64 + wm * 32;
    const int nb = blockIdx.x * 64;
    const int z = blockIdx.z;

    // stage: coalesced f32 row reads -> bf16 transpose-store
#pragma unroll
    for (int kc = 0; kc < 256; kc += 64) {
#pragma unroll
        for (int p = 0; p < 16; ++p) {
            int idx = p * 256 + tid;
            int kk = idx >> 6, nn = idx & 63;
            Bs[nn][kc + kk] = f2bf(x[(size_t)(kc + kk) * NPTS + nb + nn]);
        }
    }
    __syncthreads();

    const float* A    = (z == 0) ? Wq : (z == 1) ? Wk : Wv;
    const float* bias = (z == 0) ? bq : (z == 1) ? bk : bv;
    ushort_t* dst     = (z == 0) ? Qf : (z == 1) ? Kf : Vf;
    const float scl   = (z == 0) ? 0.125f : 1.0f;

    f32x4 acc[2][2];
#pragma unroll
    for (int i = 0; i < 2; ++i)
#pragma unroll
        for (int j = 0; j < 2; ++j) acc[i][j] = (f32x4){0.f, 0.f, 0.f, 0.f};

    for (int k0 = 0; k0 < D_CH; k0 += 32) {
        bf16x8 af[2], bfr[2];
#pragma unroll
        for (int mf = 0; mf < 2; ++mf) {
            const float* ap = A + (size_t)(m0 + mf * 16 + l15) * D_CH + k0 + lhi * 8;
            float4 a0 = *(const float4*)ap;
            float4 a1 = *(const float4*)(ap + 4);
            unsigned* tp = (unsigned*)&af[mf];
            tp[0] = cvt_pk(a0.x, a0.y);
            tp[1] = cvt_pk(a0.z, a0.w);
            tp[2] = cvt_pk(a1.x, a1.y);
            tp[3] = cvt_pk(a1.z, a1.w);
        }
#pragma unroll
        for (int nf = 0; nf < 2; ++nf)
            bfr[nf] = *(const bf16x8*)&Bs[wn * 32 + nf * 16 + l15][k0 + lhi * 8];
#pragma unroll
        for (int mf = 0; mf < 2; ++mf)
#pragma unroll
            for (int nf = 0; nf < 2; ++nf)
                acc[mf][nf] = __builtin_amdgcn_mfma_f32_16x16x32_bf16(af[mf], bfr[nf], acc[mf][nf], 0, 0, 0);
    }

#pragma unroll
    for (int mf = 0; mf < 2; ++mf) {
#pragma unroll
        for (int r = 0; r < 4; ++r) {
            int m = m0 + mf * 16 + lhi * 4 + r;
            int head = m >> 6, dch = m & 63;
            float bi = bias[m];
#pragma unroll
            for (int nf = 0; nf < 2; ++nf) {
                int n = nb + wn * 32 + nf * 16 + l15;
                float v = (acc[mf][nf][r] + bi) * scl;
                size_t idx;
                if (z < 2)
                    idx = (size_t)head * HSTRIDE + (size_t)(n >> 4) * 1024 + (dch >> 5) * 512
                        + (((dch >> 3) & 3) * 16 + (n & 15)) * 8 + (dch & 7);
                else
                    idx = (size_t)head * HSTRIDE + (size_t)(n >> 6) * 4096 + (dch >> 4) * 1024
                        + ((n >> 5) & 1) * 512 + (((n >> 3) & 3) * 16 + (dch & 15)) * 8 + (n & 7);
                dst[idx] = (ushort_t)(cvt_pk(v, v) & 0xFFFF);
            }
        }
    }
}

// ---------------------------------------------------------------------------
// One 64-key attention tile (r18/r20 ordering — measured best).
// ---------------------------------------------------------------------------
__device__ __forceinline__ void attn_tile(
    int kt, int ktn, const float* __restrict__ Sg,
    const ushort_t* __restrict__ Kh, const ushort_t* __restrict__ Vh,
    const bf16x8 (&qf)[2][2],
    ushort_t (* __restrict__ Sw)[72],
    f32x4 (&macc)[2][4], float (&lrun)[2],
    ushort_t (* __restrict__ Pw)[72], int l15, int lhi, int lane)
{
    // issue next tile's mask loads (8 instr, 4x256B segments each)
    f32x4 sr[8];
#pragma unroll
    for (int p = 0; p < 8; ++p)
        sr[p] = *(const f32x4*)&Sg[(size_t)p * 4 * NPTS + (size_t)ktn * 64];

    // QK^T swapped for both q-frags: sacc[f][kb][r] = score[key][q=f*16+l15]
    f32x4 sacc0[4], sacc1[4];
    __builtin_amdgcn_s_setprio(1);
#pragma unroll
    for (int kb = 0; kb < 4; ++kb) {
        const ushort_t* kp = Kh + (size_t)(kt * 4 + kb) * 1024 + lane * 8;
        bf16x8 kf0 = *(const bf16x8*)kp;
        bf16x8 kf1 = *(const bf16x8*)(kp + 512);
        f32x4 z0 = (f32x4){0.f, 0.f, 0.f, 0.f};
        z0 = __builtin_amdgcn_mfma_f32_16x16x32_bf16(kf0, qf[0][0], z0, 0, 0, 0);
        z0 = __builtin_amdgcn_mfma_f32_16x16x32_bf16(kf1, qf[0][1], z0, 0, 0, 0);
        sacc0[kb] = z0;
        f32x4 z1 = (f32x4){0.f, 0.f, 0.f, 0.f};
        z1 = __builtin_amdgcn_mfma_f32_16x16x32_bf16(kf0, qf[1][0], z1, 0, 0, 0);
        z1 = __builtin_amdgcn_mfma_f32_16x16x32_bf16(kf1, qf[1][1], z1, 0, 0, 0);
        sacc1[kb] = z1;
    }
    __builtin_amdgcn_s_setprio(0);

    // issue V loads (shared by both fragments)
    bf16x8 vf[8];
    const ushort_t* vb = Vh + (size_t)kt * 4096 + lane * 8;
#pragma unroll
    for (int mm = 0; mm < 2; ++mm)
#pragma unroll
        for (int db = 0; db < 4; ++db)
            vf[mm * 4 + db] = *(const bf16x8*)(vb + db * 1024 + mm * 512);

    // p = exp(score * mask), both fragments; pack (HW cvt) -> P_lds
    float ts0 = 0.0f, ts1 = 0.0f;
#pragma unroll
    for (int kb = 0; kb < 4; ++kb) {
        unsigned a0 = *(const unsigned*)&Sw[l15][kb * 16 + lhi * 4];
        unsigned a1 = *(const unsigned*)&Sw[l15][kb * 16 + lhi * 4 + 2];
        unsigned b0 = *(const unsigned*)&Sw[16 + l15][kb * 16 + lhi * 4];
        unsigned b1 = *(const unsigned*)&Sw[16 + l15][kb * 16 + lhi * 4 + 2];
        float p00 = __expf(sacc0[kb][0] * bf2f((ushort_t)(a0 & 0xFFFF)));
        float p01 = __expf(sacc0[kb][1] * bf2f((ushort_t)(a0 >> 16)));
        float p02 = __expf(sacc0[kb][2] * bf2f((ushort_t)(a1 & 0xFFFF)));
        float p03 = __expf(sacc0[kb][3] * bf2f((ushort_t)(a1 >> 16)));
        float p10 = __expf(sacc1[kb][0] * bf2f((ushort_t)(b0 & 0xFFFF)));
        float p11 = __expf(sacc1[kb][1] * bf2f((ushort_t)(b0 >> 16)));
        float p12 = __expf(sacc1[kb][2] * bf2f((ushort_t)(b1 & 0xFFFF)));
        float p13 = __expf(sacc1[kb][3] * bf2f((ushort_t)(b1 >> 16)));
        ts0 += (p00 + p01) + (p02 + p03);
        ts1 += (p10 + p11) + (p12 + p13);
        *(unsigned*)&Pw[l15][kb * 16 + lhi * 4]          = cvt_pk(p00, p01);
        *(unsigned*)&Pw[l15][kb * 16 + lhi * 4 + 2]      = cvt_pk(p02, p03);
        *(unsigned*)&Pw[16 + l15][kb * 16 + lhi * 4]     = cvt_pk(p10, p11);
        *(unsigned*)&Pw[16 + l15][kb * 16 + lhi * 4 + 2] = cvt_pk(p12, p13);
    }
    lrun[0] += ts0;
    lrun[1] += ts1;

    // store next tile's mask (all Sw reads done; sr regs die here)
#pragma unroll
    for (int p = 0; p < 8; ++p) {
        *(unsigned*)&Sw[p * 4 + lhi][l15 * 4]     = cvt_pk(sr[p][0], sr[p][1]);
        *(unsigned*)&Sw[p * 4 + lhi][l15 * 4 + 2] = cvt_pk(sr[p][2], sr[p][3]);
    }

    // PV: mfma(A=V row=d, B=P col=q), both fragments share vf
    __builtin_amdgcn_s_setprio(1);
#pragma unroll
    for (int mm = 0; mm < 2; ++mm) {
        bf16x8 pf0 = *(const bf16x8*)&Pw[l15][mm * 32 + lhi * 8];
        bf16x8 pf1 = *(const bf16x8*)&Pw[16 + l15][mm * 32 + lhi * 8];
#pragma unroll
        for (int db = 0; db < 4; ++db) {
            macc[0][db] = __builtin_amdgcn_mfma_f32_16x16x32_bf16(vf[mm * 4 + db], pf0, macc[0][db], 0, 0, 0);
            macc[1][db] = __builtin_amdgcn_mfma_f32_16x16x32_bf16(vf[mm * 4 + db], pf1, macc[1][db], 0, 0, 0);
        }
    }
    __builtin_amdgcn_s_setprio(0);
}

// ---------------------------------------------------------------------------
// MFMA flash attention (r20 form): 32 q/warp, per-head blocks, key-split 8.
// Grid (32, NHEAD, KSPLIT); block 256.
// ---------------------------------------------------------------------------
__global__ __launch_bounds__(256, 3) void attn_mfma(
    const ushort_t* __restrict__ Qf, const ushort_t* __restrict__ Kf,
    const ushort_t* __restrict__ Vf, const float* __restrict__ S,
    ushort_t* __restrict__ pacc, float* __restrict__ pl)
{
    __shared__ __align__(16) ushort_t P_lds[4][32][72];   // 18432 B
    __shared__ __align__(16) ushort_t S_lds[4][32][72];   // 18432 B

    const int tid  = threadIdx.x;
    const int w    = tid >> 6;
    const int lane = tid & 63;
    const int l15  = lane & 15;
    const int lhi  = lane >> 4;
    const int h    = blockIdx.y;
    const int ks   = blockIdx.z;
    const int q0   = blockIdx.x * 128 + w * 32;
    const int ktb  = ks * (KCHUNK / 64);

    const ushort_t* Kh = Kf + (size_t)h * HSTRIDE;
    const ushort_t* Vh = Vf + (size_t)h * HSTRIDE;
    const float* Sg = S + (size_t)(q0 + lhi) * NPTS + l15 * 4;
    ushort_t (* __restrict__ Pw)[72] = P_lds[w];
    ushort_t (* __restrict__ Sw)[72] = S_lds[w];

    bf16x8 qf[2][2];
#pragma unroll
    for (int f = 0; f < 2; ++f) {
        const ushort_t* qp = Qf + (size_t)h * HSTRIDE
                           + (size_t)((q0 + f * 16) >> 4) * 1024 + lane * 8;
        qf[f][0] = *(const bf16x8*)qp;
        qf[f][1] = *(const bf16x8*)(qp + 512);
    }

    f32x4 macc[2][4];
#pragma unroll
    for (int f = 0; f < 2; ++f)
#pragma unroll
        for (int db = 0; db < 4; ++db) macc[f][db] = (f32x4){0.f, 0.f, 0.f, 0.f};
    float lrun[2] = {0.0f, 0.0f};

    // prologue: stage mask tile ktb
    {
#pragma unroll
        for (int p = 0; p < 8; ++p) {
            f32x4 t = *(const f32x4*)&Sg[(size_t)p * 4 * NPTS + (size_t)ktb * 64];
            *(unsigned*)&Sw[p * 4 + lhi][l15 * 4]     = cvt_pk(t[0], t[1]);
            *(unsigned*)&Sw[p * 4 + lhi][l15 * 4 + 2] = cvt_pk(t[2], t[3]);
        }
    }

    // 8 tiles; prefetch distance 1 (wrap on last is harmless)
    for (int kt = ktb; kt < ktb + 8; ++kt) {
        const int ktn = (kt + 1 < ktb + 8) ? kt + 1 : ktb;
        attn_tile(kt, ktn, Sg, Kh, Vh, qf, Sw, macc, lrun, Pw, l15, lhi, lane);
    }

    // deferred cross-group l reduction (once per block)
#pragma unroll
    for (int f = 0; f < 2; ++f) {
        lrun[f] += __shfl_xor(lrun[f], 16);
        lrun[f] += __shfl_xor(lrun[f], 32);
    }

    // store unnormalized partials for both fragments
    const size_t pb = ((size_t)ks * NHEAD + h) * NPTS;
#pragma unroll
    for (int f = 0; f < 2; ++f) {
        ushort_t* prow = pacc + (pb + q0 + f * 16 + l15) * DHEAD;
#pragma unroll
        for (int db = 0; db < 4; ++db) {
            *(unsigned*)&prow[db * 16 + lhi * 4]     = cvt_pk(macc[f][db][0], macc[f][db][1]);
            *(unsigned*)&prow[db * 16 + lhi * 4 + 2] = cvt_pk(macc[f][db][2], macc[f][db][3]);
        }
    }
    if (lane < 16) {
        pl[pb + q0 + lane]      = lrun[0];
        pl[pb + q0 + 16 + lane] = lrun[1];
    }
}

// ---------------------------------------------------------------------------
// FUSED MERGE + MLP on 16-point blocks (r19/r20 form).
// ---------------------------------------------------------------------------
__global__ __launch_bounds__(256) void mlp_fused(
    const ushort_t* __restrict__ pacc, const float* __restrict__ pl,
    ushort_t* __restrict__ msgT,
    const float* __restrict__ W1, const float* __restrict__ b1,
    const float* __restrict__ g1, const float* __restrict__ be1,
    const float* __restrict__ W2, const float* __restrict__ b2,
    const float* __restrict__ g2, const float* __restrict__ be2,
    const float* __restrict__ W3, const float* __restrict__ b3,
    const float* __restrict__ x, float* __restrict__ out,
    ushort_t* __restrict__ h1T, ushort_t* __restrict__ h2T)
{
    const int tid = threadIdx.x;
    const int w = tid >> 6, lane = tid & 63, l15 = lane & 15, lhi = lane >> 4;
    const int nblk = blockIdx.x * 16;

    // --- Phase A: merge partials -> msgT (16 rows; 2 heads per thread-half)
    {
        const int hb  = (tid >> 7) * 2;       // 0 or 2
        const int loc = tid & 127;
        const int ql  = loc >> 3;             // 0..15
        const int d0  = (loc & 7) * 8;        // 0..56
#pragma unroll
        for (int hh = 0; hh < 2; ++hh) {
            const int h = hb + hh;
            float ls = 0.0f;
#pragma unroll
            for (int ks = 0; ks < KSPLIT; ++ks)
                ls += pl[((size_t)ks * NHEAD + h) * NPTS + nblk + ql];
            float inv = 1.0f / ls;
            float o[8];
#pragma unroll
            for (int j = 0; j < 8; ++j) o[j] = 0.0f;
#pragma unroll
            for (int ks = 0; ks < KSPLIT; ++ks) {
                const ushort_t* ap = pacc
                    + (((size_t)ks * NHEAD + h) * NPTS + nblk + ql) * DHEAD + d0;
                bf16x8 v = *(const bf16x8*)ap;
#pragma unroll
                for (int j = 0; j < 8; ++j) o[j] += bf2f((ushort_t)v[j]);
            }
            unsigned* dp = (unsigned*)(msgT + (size_t)(nblk + ql) * D_CH + h * 64 + d0);
            dp[0] = cvt_pk(o[0] * inv, o[1] * inv);
            dp[1] = cvt_pk(o[2] * inv, o[3] * inv);
            dp[2] = cvt_pk(o[4] * inv, o[5] * inv);
            dp[3] = cvt_pk(o[6] * inv, o[7] * inv);
        }
    }
    __syncthreads();

    // --- Phase B: h1 = relu(bn1(W1 . msg)), M=128 K=256, n=16 --------------
    {
        f32x4 acc[2];
        acc[0] = (f32x4){0.f, 0.f, 0.f, 0.f};
        acc[1] = (f32x4){0.f, 0.f, 0.f, 0.f};
        const ushort_t* Bt = msgT + (size_t)nblk * D_CH;
        for (int k0 = 0; k0 < 256; k0 += 32) {
            bf16x8 bfr = *(const bf16x8*)&Bt[(size_t)l15 * D_CH + k0 + lhi * 8];
#pragma unroll
            for (int mf = 0; mf < 2; ++mf) {
                const float* ap = W1 + (size_t)(w * 32 + mf * 16 + l15) * 256 + k0 + lhi * 8;
                float4 a0 = *(const float4*)ap;
                float4 a1 = *(const float4*)(ap + 4);
                bf16x8 af;
                unsigned* tp = (unsigned*)&af;
                tp[0] = cvt_pk(a0.x, a0.y); tp[1] = cvt_pk(a0.z, a0.w);
                tp[2] = cvt_pk(a1.x, a1.y); tp[3] = cvt_pk(a1.z, a1.w);
                acc[mf] = __builtin_amdgcn_mfma_f32_16x16x32_bf16(af, bfr, acc[mf], 0, 0, 0);
            }
        }
#pragma unroll
        for (int mf = 0; mf < 2; ++mf)
#pragma unroll
            for (int r = 0; r < 4; ++r) {
                int m = w * 32 + mf * 16 + lhi * 4 + r;
                float bi = b1[m], sc = g1[m] * BN_RSQ, sh = be1[m];
                float v = fmaxf((acc[mf][r] + bi) * sc + sh, 0.0f);
                h1T[(size_t)(nblk + l15) * 128 + m] = (ushort_t)(cvt_pk(v, v) & 0xFFFF);
            }
    }
    __syncthreads();

    // --- Phase C: h2 = relu(bn2(W2 . h1)), M=128 K=128, n=16 ----------------
    {
        f32x4 acc[2];
        acc[0] = (f32x4){0.f, 0.f, 0.f, 0.f};
        acc[1] = (f32x4){0.f, 0.f, 0.f, 0.f};
        const ushort_t* Bt = h1T + (size_t)nblk * 128;
        for (int k0 = 0; k0 < 128; k0 += 32) {
            bf16x8 bfr = *(const bf16x8*)&Bt[(size_t)l15 * 128 + k0 + lhi * 8];
#pragma unroll
            for (int mf = 0; mf < 2; ++mf) {
                const float* ap = W2 + (size_t)(w * 32 + mf * 16 + l15) * 128 + k0 + lhi * 8;
                float4 a0 = *(const float4*)ap;
                float4 a1 = *(const float4*)(ap + 4);
                bf16x8 af;
                unsigned* tp = (unsigned*)&af;
                tp[0] = cvt_pk(a0.x, a0.y); tp[1] = cvt_pk(a0.z, a0.w);
                tp[2] = cvt_pk(a1.x, a1.y); tp[3] = cvt_pk(a1.z, a1.w);
                acc[mf] = __builtin_amdgcn_mfma_f32_16x16x32_bf16(af, bfr, acc[mf], 0, 0, 0);
            }
        }
#pragma unroll
        for (int mf = 0; mf < 2; ++mf)
#pragma unroll
            for (int r = 0; r < 4; ++r) {
                int m = w * 32 + mf * 16 + lhi * 4 + r;
                float bi = b2[m], sc = g2[m] * BN_RSQ, sh = be2[m];
                float v = fmaxf((acc[mf][r] + bi) * sc + sh, 0.0f);
                h2T[(size_t)(nblk + l15) * 128 + m] = (ushort_t)(cvt_pk(v, v) & 0xFFFF);
            }
    }
    __syncthreads();

    // --- Phase D: out = x + W3 . h2, M=256 K=128, n=16 ----------------------
    {
        f32x4 acc[4];
#pragma unroll
        for (int i = 0; i < 4; ++i) acc[i] = (f32x4){0.f, 0.f, 0.f, 0.f};
        const ushort_t* Bt = h2T + (size_t)nblk * 128;
        for (int k0 = 0; k0 < 128; k0 += 32) {
            bf16x8 bfr = *(const bf16x8*)&Bt[(size_t)l15 * 128 + k0 + lhi * 8];
#pragma unroll
            for (int mf = 0; mf < 4; ++mf) {
                const float* ap = W3 + (size_t)(w * 64 + mf * 16 + l15) * 128 + k0 + lhi * 8;
                float4 a0 = *(const float4*)ap;
                float4 a1 = *(const float4*)(ap + 4);
                bf16x8 af;
                unsigned* tp = (unsigned*)&af;
                tp[0] = cvt_pk(a0.x, a0.y); tp[1] = cvt_pk(a0.z, a0.w);
                tp[2] = cvt_pk(a1.x, a1.y); tp[3] = cvt_pk(a1.z, a1.w);
                acc[mf] = __builtin_amdgcn_mfma_f32_16x16x32_bf16(af, bfr, acc[mf], 0, 0, 0);
            }
        }
#pragma unroll
        for (int mf = 0; mf < 4; ++mf)
#pragma unroll
            for (int r = 0; r < 4; ++r) {
                int m = w * 64 + mf * 16 + lhi * 4 + r;
                float bi = b3[m];
                int n = nblk + l15;
                out[(size_t)m * NPTS + n] = acc[mf][r] + bi + x[(size_t)m * NPTS + n];
            }
    }
}

// ---------------------------------------------------------------------------
extern "C" void kernel_launch(void* const* d_in, const int* in_sizes, int n_in,
                              void* d_out, int out_size, void* d_ws, size_t ws_size,
                              hipStream_t stream) {
    const float* x  = (const float*)d_in[0];
    const float* S  = (const float*)d_in[1];
    const float* Wq = (const float*)d_in[2];
    const float* bq = (const float*)d_in[3];
    const float* Wk = (const float*)d_in[4];
    const float* bk = (const float*)d_in[5];
    const float* Wv = (const float*)d_in[6];
    const float* bv = (const float*)d_in[7];
    const float* W1 = (const float*)d_in[8];
    const float* b1 = (const float*)d_in[9];
    const float* g1 = (const float*)d_in[10];
    const float* be1= (const float*)d_in[11];
    const float* W2 = (const float*)d_in[12];
    const float* b2 = (const float*)d_in[13];
    const float* g2 = (const float*)d_in[14];
    const float* be2= (const float*)d_in[15];
    const float* W3 = (const float*)d_in[16];
    const float* b3 = (const float*)d_in[17];

    char* ws = (char*)d_ws;
    const size_t MB = 1024 * 1024;
    ushort_t* Qf   = (ushort_t*)(ws + 2 * MB);               // 2 MB
    ushort_t* Kf   = (ushort_t*)(ws + 4 * MB);               // 2 MB
    ushort_t* Vf   = (ushort_t*)(ws + 6 * MB);               // 2 MB
    ushort_t* pacc = (ushort_t*)(ws + 8 * MB);               // 16 MB
    float*    pl   = (float*)   (ws + 24 * MB);              // 512 KB
    ushort_t* msgT = (ushort_t*)(ws + 25 * MB);              // 2 MB
    ushort_t* h1T  = (ushort_t*)(ws + 27 * MB);              // 1 MB
    ushort_t* h2T  = (ushort_t*)(ws + 28 * MB);              // 1 MB

    gemm_qkv<<<dim3(64, 4, 3), 256, 0, stream>>>(Wq, bq, Wk, bk, Wv, bv, x, Qf, Kf, Vf);

    attn_mfma<<<dim3(32, NHEAD, KSPLIT), 256, 0, stream>>>(Qf, Kf, Vf, S, pacc, pl);

    mlp_fused<<<dim3(256), 256, 0, stream>>>(pacc, pl, msgT,
        W1, b1, g1, be1, W2, b2, g2, be2, W3, b3, x, (float*)d_out, h1T, h2T);
}